// Round 1
// baseline (359.873 us; speedup 1.0000x reference)
//
#include <hip/hip_runtime.h>
#include <hip/hip_bf16.h>

#define NNODES 90112
#define BGRAPH 4096
#define NPG 22
#define DBB 256
#define DNODE 128
#define DPROJ 256
#define DGIN 64
#define DGOUT 128

// ws layout (bf16 elems):
//   [0,        32768)  WTp   [256 cols][128 k]   (w_proj^T)
//   [32768,   622592)  WTg   [768 cols][768 k]   (cols: z|r|h gates; k: z|x_proj|prev_h)
//   [622592,  688128)  WThh  [256 cols][256 k]
// then f32 at byte offset 688128*2: bz[256], br[256], bh[256] (combined biases)
#define WTG_OFF   32768
#define WTHH_OFF  622592
#define WS_BF16_ELEMS 688128

typedef __attribute__((ext_vector_type(8))) short bf16x8;
typedef __attribute__((ext_vector_type(4))) float f32x4;

__device__ __forceinline__ short f2bf(float f) {
  __hip_bfloat16 h = __float2bfloat16(f);
  return *reinterpret_cast<short*>(&h);
}

__global__ void pack_weights(const float* __restrict__ w_proj,
                             const float* __restrict__ W_xz, const float* __restrict__ W_hz,
                             const float* __restrict__ W_xr, const float* __restrict__ W_hr,
                             const float* __restrict__ W_xh, const float* __restrict__ W_hh,
                             const float* __restrict__ b_xz, const float* __restrict__ b_hz,
                             const float* __restrict__ b_xr, const float* __restrict__ b_hr,
                             const float* __restrict__ b_xh, const float* __restrict__ b_hh,
                             __hip_bfloat16* __restrict__ wsb, float* __restrict__ wsf) {
  int i = blockIdx.x * 256 + threadIdx.x;
  if (i < 32768) {
    int c = i >> 7, k = i & 127;                 // WTp[c][k] = w_proj[k][c]
    wsb[i] = __float2bfloat16(w_proj[k * DPROJ + c]);
  } else if (i < WTHH_OFF) {
    int j = i - WTG_OFF;
    int c = j / 768, k = j - c * 768;
    const float* Wx; const float* Wh; int cc;
    if (c < 256)      { Wx = W_xz; Wh = W_hz; cc = c; }
    else if (c < 512) { Wx = W_xr; Wh = W_hr; cc = c - 256; }
    else              { Wx = W_xh; Wh = nullptr; cc = c - 512; }
    float v;
    if (k < 512) v = Wx[k * 256 + cc];
    else         v = Wh ? Wh[(k - 512) * 256 + cc] : 0.0f;
    wsb[i] = __float2bfloat16(v);
  } else if (i < WS_BF16_ELEMS) {
    int j = i - WTHH_OFF;
    int c = j >> 8, k = j & 255;                 // WThh[c][k] = W_hh[k][c]
    wsb[i] = __float2bfloat16(W_hh[k * 256 + c]);
  }
  if (i < 256) {
    wsf[i]       = b_xz[i] + b_hz[i];
    wsf[256 + i] = b_xr[i] + b_hr[i];
    wsf[512 + i] = b_xh[i] + b_hh[i];
  }
}

// fused[b] = [ mean_{22 rows} z , relu(u @ w_glob + b_glob) ]
__global__ void fused_head(const float* __restrict__ z, const float* __restrict__ u,
                           const float* __restrict__ w_glob, const float* __restrict__ b_glob,
                           float* __restrict__ out) {
  int b = blockIdx.x;
  int t = threadIdx.x;  // 128 threads
  __shared__ float us[DGIN];
  if (t < DGIN) us[t] = u[b * DGIN + t];
  __syncthreads();
  const float* zb = z + (size_t)b * NPG * DBB;
  #pragma unroll
  for (int half = 0; half < 2; ++half) {
    int c = t + half * 128;
    float s = 0.f;
    #pragma unroll
    for (int r = 0; r < NPG; ++r) s += zb[r * DBB + c];
    out[(size_t)b * 384 + c] = s * (1.0f / NPG);
  }
  float acc = b_glob[t];
  #pragma unroll
  for (int k = 0; k < DGIN; ++k) acc += us[k] * w_glob[k * DGOUT + t];
  out[(size_t)b * 384 + 256 + t] = fmaxf(acc, 0.f);
}

// Fully fused GRU body: 64 rows/block, 512 threads (8 waves x 32 output cols).
__global__ __launch_bounds__(512, 2)
void grnn_main(const float* __restrict__ z, const float* __restrict__ x,
               const float* __restrict__ prev_h, const float* __restrict__ b_proj,
               const __hip_bfloat16* __restrict__ wsb, const float* __restrict__ wsf,
               float* __restrict__ h_out) {
  __shared__ __hip_bfloat16 zt[64][256];   // z tile; later reused for T = prev_h * R
  __shared__ __hip_bfloat16 xp[64][256];   // x_proj tile
  __shared__ __hip_bfloat16 pht[64][256];  // prev_h tile
  __shared__ __hip_bfloat16 xs[64][128];   // x tile

  const int r0   = blockIdx.x * 64;
  const int tid  = threadIdx.x;
  const int wid  = tid >> 6;
  const int lane = tid & 63;
  const int l15  = lane & 15;
  const int lg   = lane >> 4;

  // ---- stage inputs to LDS as bf16, XOR-swizzled in 16B (8-elem) granules ----
  #pragma unroll
  for (int i = 0; i < 4; ++i) {
    int g = tid + i * 512;
    int row = g >> 5, c8 = g & 31;
    const float* p = z + (size_t)(r0 + row) * DBB + c8 * 8;
    bf16x8 o;
    #pragma unroll
    for (int j = 0; j < 8; ++j) o[j] = f2bf(p[j]);
    *(bf16x8*)&zt[row][(c8 ^ (row & 7)) * 8] = o;
  }
  #pragma unroll
  for (int i = 0; i < 4; ++i) {
    int g = tid + i * 512;
    int row = g >> 5, c8 = g & 31;
    const float* p = prev_h + (size_t)(r0 + row) * DBB + c8 * 8;
    bf16x8 o;
    #pragma unroll
    for (int j = 0; j < 8; ++j) o[j] = f2bf(p[j]);
    *(bf16x8*)&pht[row][(c8 ^ (row & 7)) * 8] = o;
  }
  #pragma unroll
  for (int i = 0; i < 2; ++i) {
    int g = tid + i * 512;
    int row = g >> 4, c8 = g & 15;
    const float* p = x + (size_t)(r0 + row) * DNODE + c8 * 8;
    bf16x8 o;
    #pragma unroll
    for (int j = 0; j < 8; ++j) o[j] = f2bf(p[j]);
    *(bf16x8*)&xs[row][(c8 ^ (row & 7)) * 8] = o;
  }
  __syncthreads();

  // K=256 tile GEMM helper: acc[mt][nt] += tile(64xK=256) @ WT(cols from wt)
  auto mm256 = [&](const __hip_bfloat16 (&tile)[64][256], const __hip_bfloat16* wt,
                   int wtld, f32x4 (&acc)[4][2]) {
    #pragma unroll 2
    for (int kb = 0; kb < 8; ++kb) {
      bf16x8 a[4];
      int gk = kb * 4 + lg;
      #pragma unroll
      for (int mt = 0; mt < 4; ++mt) {
        int row = mt * 16 + l15;
        a[mt] = *(const bf16x8*)&tile[row][(gk ^ (row & 7)) * 8];
      }
      bf16x8 b[2];
      #pragma unroll
      for (int nt = 0; nt < 2; ++nt) {
        int col = wid * 32 + nt * 16 + l15;
        b[nt] = *(const bf16x8*)(wt + (size_t)col * wtld + kb * 32 + lg * 8);
      }
      #pragma unroll
      for (int nt = 0; nt < 2; ++nt)
        #pragma unroll
        for (int mt = 0; mt < 4; ++mt)
          acc[mt][nt] = __builtin_amdgcn_mfma_f32_16x16x32_bf16(a[mt], b[nt], acc[mt][nt], 0, 0, 0);
    }
  };

  // ---- x_proj = relu(x @ w_proj + b_proj)  (K=128) ----
  {
    f32x4 accp[4][2] = {};
    #pragma unroll
    for (int kb = 0; kb < 4; ++kb) {
      bf16x8 a[4];
      int gk = kb * 4 + lg;
      #pragma unroll
      for (int mt = 0; mt < 4; ++mt) {
        int row = mt * 16 + l15;
        a[mt] = *(const bf16x8*)&xs[row][(gk ^ (row & 7)) * 8];
      }
      bf16x8 b[2];
      #pragma unroll
      for (int nt = 0; nt < 2; ++nt) {
        int col = wid * 32 + nt * 16 + l15;
        b[nt] = *(const bf16x8*)(wsb + (size_t)col * DNODE + kb * 32 + lg * 8);
      }
      #pragma unroll
      for (int nt = 0; nt < 2; ++nt)
        #pragma unroll
        for (int mt = 0; mt < 4; ++mt)
          accp[mt][nt] = __builtin_amdgcn_mfma_f32_16x16x32_bf16(a[mt], b[nt], accp[mt][nt], 0, 0, 0);
    }
    #pragma unroll
    for (int nt = 0; nt < 2; ++nt) {
      int col = wid * 32 + nt * 16 + l15;
      float bp = b_proj[col];
      #pragma unroll
      for (int mt = 0; mt < 4; ++mt)
        #pragma unroll
        for (int j = 0; j < 4; ++j) {
          int row = mt * 16 + lg * 4 + j;
          float v = fmaxf(accp[mt][nt][j] + bp, 0.0f);
          xp[row][(((col >> 3) ^ (row & 7)) << 3) + (col & 7)] = __float2bfloat16(v);
        }
    }
  }
  __syncthreads();

  // ---- gates ----
  const __hip_bfloat16* WTG = wsb + WTG_OFF;
  f32x4 accz[4][2] = {};
  mm256(zt,  WTG + 0,   768, accz);
  mm256(xp,  WTG + 256, 768, accz);
  mm256(pht, WTG + 512, 768, accz);
  f32x4 accr[4][2] = {};
  mm256(zt,  WTG + (size_t)256 * 768 + 0,   768, accr);
  mm256(xp,  WTG + (size_t)256 * 768 + 256, 768, accr);
  mm256(pht, WTG + (size_t)256 * 768 + 512, 768, accr);
  f32x4 acch[4][2] = {};
  mm256(zt,  WTG + (size_t)512 * 768 + 0,   768, acch);
  mm256(xp,  WTG + (size_t)512 * 768 + 256, 768, acch);

  __syncthreads();  // everyone done reading zt
  // T = prev_h * sigmoid(A_r + br)  -> overwrite zt
  #pragma unroll
  for (int nt = 0; nt < 2; ++nt) {
    int col = wid * 32 + nt * 16 + l15;
    float br = wsf[256 + col];
    #pragma unroll
    for (int mt = 0; mt < 4; ++mt)
      #pragma unroll
      for (int j = 0; j < 4; ++j) {
        int row = mt * 16 + lg * 4 + j;
        float rr = 1.0f / (1.0f + __expf(-(accr[mt][nt][j] + br)));
        float ph = prev_h[(size_t)(r0 + row) * DBB + col];
        zt[row][(((col >> 3) ^ (row & 7)) << 3) + (col & 7)] = __float2bfloat16(ph * rr);
      }
  }
  __syncthreads();
  mm256(zt, wsb + WTHH_OFF, 256, acch);  // += T @ W_hh

  // ---- epilogue: h = Z*prev_h + (1-Z)*tanh(A_h + bh) ----
  #pragma unroll
  for (int nt = 0; nt < 2; ++nt) {
    int col = wid * 32 + nt * 16 + l15;
    float bz = wsf[col];
    float bh = wsf[512 + col];
    #pragma unroll
    for (int mt = 0; mt < 4; ++mt)
      #pragma unroll
      for (int j = 0; j < 4; ++j) {
        int row = mt * 16 + lg * 4 + j;
        size_t idx = (size_t)(r0 + row) * DBB + col;
        float zg = 1.0f / (1.0f + __expf(-(accz[mt][nt][j] + bz)));
        float ht = tanhf(acch[mt][nt][j] + bh);
        float ph = prev_h[idx];
        h_out[idx] = zg * ph + (1.0f - zg) * ht;
      }
  }
}

extern "C" void kernel_launch(void* const* d_in, const int* in_sizes, int n_in,
                              void* d_out, int out_size, void* d_ws, size_t ws_size,
                              hipStream_t stream) {
  const float* z      = (const float*)d_in[0];
  const float* u      = (const float*)d_in[1];
  const float* x      = (const float*)d_in[2];
  const float* prev_h = (const float*)d_in[6];
  const float* w_proj = (const float*)d_in[7];
  const float* b_proj = (const float*)d_in[8];
  const float* w_glob = (const float*)d_in[9];
  const float* b_glob = (const float*)d_in[10];
  const float* W_xz   = (const float*)d_in[11];
  const float* b_xz   = (const float*)d_in[12];
  const float* W_hz   = (const float*)d_in[13];
  const float* b_hz   = (const float*)d_in[14];
  const float* W_xr   = (const float*)d_in[15];
  const float* b_xr   = (const float*)d_in[16];
  const float* W_hr   = (const float*)d_in[17];
  const float* b_hr   = (const float*)d_in[18];
  const float* W_xh   = (const float*)d_in[19];
  const float* b_xh   = (const float*)d_in[20];
  const float* W_hh   = (const float*)d_in[21];
  const float* b_hh   = (const float*)d_in[22];

  __hip_bfloat16* wsb = (__hip_bfloat16*)d_ws;
  float* wsf = (float*)((char*)d_ws + (size_t)WS_BF16_ELEMS * 2);

  float* fused = (float*)d_out;
  float* h_out = fused + (size_t)BGRAPH * 384;

  pack_weights<<<dim3(WS_BF16_ELEMS / 256), dim3(256), 0, stream>>>(
      w_proj, W_xz, W_hz, W_xr, W_hr, W_xh, W_hh,
      b_xz, b_hz, b_xr, b_hr, b_xh, b_hh, wsb, wsf);

  grnn_main<<<dim3(NNODES / 64), dim3(512), 0, stream>>>(
      z, x, prev_h, b_proj, wsb, wsf, h_out);

  fused_head<<<dim3(BGRAPH), dim3(128), 0, stream>>>(z, u, w_glob, b_glob, fused);
}

// Round 2
// 320.747 us; speedup vs baseline: 1.1220x; 1.1220x over previous
//
#include <hip/hip_runtime.h>
#include <hip/hip_bf16.h>

#define NNODES 90112
#define BGRAPH 4096
#define NPG 22
#define DBB 256
#define DNODE 128
#define DPROJ 256
#define DGIN 64
#define DGOUT 128

// ws layout (bf16 elems):
//   [0,        32768)  WTp   [256 cols][128 k]   (w_proj^T)
//   [32768,   622592)  WTg   [768 cols][768 k]   (cols: z|r|h gates; k: z|x_proj|prev_h)
//   [622592,  688128)  WThh  [256 cols][256 k]
// then f32 at byte offset 688128*2: bz[256], br[256], bh[256] (combined biases)
#define WTG_OFF   32768
#define WTHH_OFF  622592
#define WS_BF16_ELEMS 688128

typedef __attribute__((ext_vector_type(8))) short bf16x8;
typedef __attribute__((ext_vector_type(4))) float f32x4;

__device__ __forceinline__ short f2bf(float f) {
  __hip_bfloat16 h = __float2bfloat16(f);
  return *reinterpret_cast<short*>(&h);
}

__device__ __forceinline__ float fsig(float xv) {
  return __fdividef(1.0f, 1.0f + __expf(-xv));
}
__device__ __forceinline__ float ftanh(float xv) {
  return 1.0f - __fdividef(2.0f, __expf(2.0f * xv) + 1.0f);
}

__global__ void pack_weights(const float* __restrict__ w_proj,
                             const float* __restrict__ W_xz, const float* __restrict__ W_hz,
                             const float* __restrict__ W_xr, const float* __restrict__ W_hr,
                             const float* __restrict__ W_xh, const float* __restrict__ W_hh,
                             const float* __restrict__ b_xz, const float* __restrict__ b_hz,
                             const float* __restrict__ b_xr, const float* __restrict__ b_hr,
                             const float* __restrict__ b_xh, const float* __restrict__ b_hh,
                             __hip_bfloat16* __restrict__ wsb, float* __restrict__ wsf) {
  int i = blockIdx.x * 256 + threadIdx.x;
  if (i < 32768) {
    int c = i >> 7, k = i & 127;                 // WTp[c][k] = w_proj[k][c]
    wsb[i] = __float2bfloat16(w_proj[k * DPROJ + c]);
  } else if (i < WTHH_OFF) {
    int j = i - WTG_OFF;
    int c = j / 768, k = j - c * 768;
    const float* Wx; const float* Wh; int cc;
    if (c < 256)      { Wx = W_xz; Wh = W_hz; cc = c; }
    else if (c < 512) { Wx = W_xr; Wh = W_hr; cc = c - 256; }
    else              { Wx = W_xh; Wh = nullptr; cc = c - 512; }
    float v;
    if (k < 512) v = Wx[k * 256 + cc];
    else         v = Wh ? Wh[(k - 512) * 256 + cc] : 0.0f;
    wsb[i] = __float2bfloat16(v);
  } else if (i < WS_BF16_ELEMS) {
    int j = i - WTHH_OFF;
    int c = j >> 8, k = j & 255;                 // WThh[c][k] = W_hh[k][c]
    wsb[i] = __float2bfloat16(W_hh[k * 256 + c]);
  }
  if (i < 256) {
    wsf[i]       = b_xz[i] + b_hz[i];
    wsf[256 + i] = b_xr[i] + b_hr[i];
    wsf[512 + i] = b_xh[i] + b_hh[i];
  }
}

// fused[b] = [ mean_{22 rows} z , relu(u @ w_glob + b_glob) ]
__global__ void fused_head(const float* __restrict__ z, const float* __restrict__ u,
                           const float* __restrict__ w_glob, const float* __restrict__ b_glob,
                           float* __restrict__ out) {
  int b = blockIdx.x;
  int t = threadIdx.x;  // 128 threads
  __shared__ float us[DGIN];
  if (t < DGIN) us[t] = u[b * DGIN + t];
  __syncthreads();
  const float* zb = z + (size_t)b * NPG * DBB;
  #pragma unroll
  for (int half = 0; half < 2; ++half) {
    int c = t + half * 128;
    float s = 0.f;
    #pragma unroll
    for (int r = 0; r < NPG; ++r) s += zb[r * DBB + c];
    out[(size_t)b * 384 + c] = s * (1.0f / NPG);
  }
  float acc = b_glob[t];
  #pragma unroll
  for (int k = 0; k < DGIN; ++k) acc += us[k] * w_glob[k * DGOUT + t];
  out[(size_t)b * 384 + 256 + t] = fmaxf(acc, 0.f);
}

// One source-tile sweep: contributes W k-rows [ksrc*256, +256) to gates z,r(,h).
template<bool DO_H>
__device__ __forceinline__ void gate_pass(
    const __hip_bfloat16* __restrict__ tile,   // [64][256] swizzled
    const __hip_bfloat16* __restrict__ WTG, int ksrc,
    int l15, int lg, int col0,
    f32x4 (&accz)[4][2], f32x4 (&accr)[4][2], f32x4 (&acch)[4][2]) {
  const __hip_bfloat16* p0 = WTG + (size_t)col0 * 768 + ksrc * 256 + lg * 8;
  const __hip_bfloat16* pz[2] = { p0,                        p0 + 16 * 768 };
  const __hip_bfloat16* pr[2] = { p0 + (size_t)256 * 768,    p0 + (size_t)(256 + 16) * 768 };
  const __hip_bfloat16* pg[2] = { p0 + (size_t)512 * 768,    p0 + (size_t)(512 + 16) * 768 };
  #pragma unroll
  for (int kb = 0; kb < 8; ++kb) {
    bf16x8 vz[2], vr[2], vh[2];
    #pragma unroll
    for (int nt = 0; nt < 2; ++nt) {
      vz[nt] = *(const bf16x8*)(pz[nt] + kb * 32);
      vr[nt] = *(const bf16x8*)(pr[nt] + kb * 32);
      if (DO_H) vh[nt] = *(const bf16x8*)(pg[nt] + kb * 32);
    }
    const int gk = kb * 4 + lg;
    bf16x8 a[4];
    #pragma unroll
    for (int mt = 0; mt < 4; ++mt) {
      const int row = mt * 16 + l15;
      a[mt] = *(const bf16x8*)(tile + row * 256 + (gk ^ (row & 7)) * 8);
    }
    #pragma unroll
    for (int nt = 0; nt < 2; ++nt)
      #pragma unroll
      for (int mt = 0; mt < 4; ++mt) {
        accz[mt][nt] = __builtin_amdgcn_mfma_f32_16x16x32_bf16(a[mt], vz[nt], accz[mt][nt], 0, 0, 0);
        accr[mt][nt] = __builtin_amdgcn_mfma_f32_16x16x32_bf16(a[mt], vr[nt], accr[mt][nt], 0, 0, 0);
        if (DO_H)
          acch[mt][nt] = __builtin_amdgcn_mfma_f32_16x16x32_bf16(a[mt], vh[nt], acch[mt][nt], 0, 0, 0);
      }
  }
}

// Fused GRU body: 64 rows/block, 512 threads (8 waves x 32 output cols).
// Phase machine with 2x32KB LDS buffers; next-phase staging loads issued
// before the current MFMA sweep, LDS writes after (latency hidden under MFMA).
__global__ __launch_bounds__(512, 2)
void grnn_main(const float* __restrict__ z, const float* __restrict__ x,
               const float* __restrict__ prev_h, const float* __restrict__ b_proj,
               const __hip_bfloat16* __restrict__ wsb, const float* __restrict__ wsf,
               float* __restrict__ h_out) {
  __shared__ __hip_bfloat16 A0[64 * 256];
  __shared__ __hip_bfloat16 A1[64 * 256];

  const int r0   = blockIdx.x * 64;
  const int tid  = threadIdx.x;
  const int wid  = tid >> 6;
  const int lane = tid & 63;
  const int l15  = lane & 15;
  const int lg   = lane >> 4;
  const int col0 = wid * 32 + l15;

  // ---- P0: stage x -> A0 (as [64][128]) ----
  #pragma unroll
  for (int i = 0; i < 2; ++i) {
    int g = tid + i * 512;
    int row = g >> 4, c8 = g & 15;
    const float* p = x + (size_t)(r0 + row) * DNODE + c8 * 8;
    float4 f0 = *(const float4*)p;
    float4 f1 = *(const float4*)(p + 4);
    bf16x8 o;
    o[0]=f2bf(f0.x); o[1]=f2bf(f0.y); o[2]=f2bf(f0.z); o[3]=f2bf(f0.w);
    o[4]=f2bf(f1.x); o[5]=f2bf(f1.y); o[6]=f2bf(f1.z); o[7]=f2bf(f1.w);
    *(bf16x8*)&A0[row * 128 + (c8 ^ (row & 7)) * 8] = o;
  }
  __syncthreads();

  // ---- P1: x_proj GEMM (reads A0) overlapped with staging z -> A1 ----
  float4 sl[8];
  #pragma unroll
  for (int i = 0; i < 4; ++i) {
    int g = tid + i * 512;
    int row = g >> 5, c8 = g & 31;
    const float* p = z + (size_t)(r0 + row) * DBB + c8 * 8;
    sl[2 * i]     = *(const float4*)p;
    sl[2 * i + 1] = *(const float4*)(p + 4);
  }
  f32x4 accp[4][2] = {};
  {
    const __hip_bfloat16* bp0 = wsb + (size_t)col0 * DNODE + lg * 8;
    const __hip_bfloat16* bp[2] = { bp0, bp0 + 16 * DNODE };
    #pragma unroll
    for (int kb = 0; kb < 4; ++kb) {
      bf16x8 vb[2];
      #pragma unroll
      for (int nt = 0; nt < 2; ++nt) vb[nt] = *(const bf16x8*)(bp[nt] + kb * 32);
      const int gk = kb * 4 + lg;
      bf16x8 a[4];
      #pragma unroll
      for (int mt = 0; mt < 4; ++mt) {
        const int row = mt * 16 + l15;
        a[mt] = *(const bf16x8*)&A0[row * 128 + (gk ^ (row & 7)) * 8];
      }
      #pragma unroll
      for (int nt = 0; nt < 2; ++nt)
        #pragma unroll
        for (int mt = 0; mt < 4; ++mt)
          accp[mt][nt] = __builtin_amdgcn_mfma_f32_16x16x32_bf16(a[mt], vb[nt], accp[mt][nt], 0, 0, 0);
    }
  }
  #pragma unroll
  for (int i = 0; i < 4; ++i) {
    int g = tid + i * 512;
    int row = g >> 5, c8 = g & 31;
    float4 f0 = sl[2 * i], f1 = sl[2 * i + 1];
    bf16x8 o;
    o[0]=f2bf(f0.x); o[1]=f2bf(f0.y); o[2]=f2bf(f0.z); o[3]=f2bf(f0.w);
    o[4]=f2bf(f1.x); o[5]=f2bf(f1.y); o[6]=f2bf(f1.z); o[7]=f2bf(f1.w);
    *(bf16x8*)&A1[row * 256 + (c8 ^ (row & 7)) * 8] = o;
  }
  __syncthreads();

  // ---- P2: write xp -> A0 (x fully consumed) ----
  {
    float bp2[2] = { b_proj[col0], b_proj[col0 + 16] };
    #pragma unroll
    for (int nt = 0; nt < 2; ++nt) {
      int col = col0 + nt * 16;
      #pragma unroll
      for (int mt = 0; mt < 4; ++mt)
        #pragma unroll
        for (int j = 0; j < 4; ++j) {
          int row = mt * 16 + lg * 4 + j;
          float v = fmaxf(accp[mt][nt][j] + bp2[nt], 0.0f);
          A0[row * 256 + ((((col >> 3) ^ (row & 7)) << 3) | (col & 7))] = __float2bfloat16(v);
        }
    }
  }
  __syncthreads();

  const __hip_bfloat16* WTG = wsb + WTG_OFF;
  f32x4 accz[4][2] = {}, accr[4][2] = {}, acch[4][2] = {};

  // ---- P3: z-tile sweep (reads A1) ----
  gate_pass<true>(A1, WTG, 0, l15, lg, col0, accz, accr, acch);
  __syncthreads();

  // ---- P4: xp sweep (reads A0) overlapped with staging prev_h -> A1 ----
  #pragma unroll
  for (int i = 0; i < 4; ++i) {
    int g = tid + i * 512;
    int row = g >> 5, c8 = g & 31;
    const float* p = prev_h + (size_t)(r0 + row) * DBB + c8 * 8;
    sl[2 * i]     = *(const float4*)p;
    sl[2 * i + 1] = *(const float4*)(p + 4);
  }
  gate_pass<true>(A0, WTG, 1, l15, lg, col0, accz, accr, acch);
  #pragma unroll
  for (int i = 0; i < 4; ++i) {
    int g = tid + i * 512;
    int row = g >> 5, c8 = g & 31;
    float4 f0 = sl[2 * i], f1 = sl[2 * i + 1];
    bf16x8 o;
    o[0]=f2bf(f0.x); o[1]=f2bf(f0.y); o[2]=f2bf(f0.z); o[3]=f2bf(f0.w);
    o[4]=f2bf(f1.x); o[5]=f2bf(f1.y); o[6]=f2bf(f1.z); o[7]=f2bf(f1.w);
    *(bf16x8*)&A1[row * 256 + (c8 ^ (row & 7)) * 8] = o;
  }
  __syncthreads();

  // ---- P5: prev_h sweep (reads A1, no h-gate) ; T = ph*sigmoid(Ar) -> A0 ----
  float ph[4][2][4];
  #pragma unroll
  for (int nt = 0; nt < 2; ++nt) {
    int col = col0 + nt * 16;
    #pragma unroll
    for (int mt = 0; mt < 4; ++mt)
      #pragma unroll
      for (int j = 0; j < 4; ++j) {
        int row = mt * 16 + lg * 4 + j;
        ph[mt][nt][j] = prev_h[(size_t)(r0 + row) * DBB + col];
      }
  }
  float brv[2] = { wsf[256 + col0], wsf[256 + col0 + 16] };
  gate_pass<false>(A1, WTG, 2, l15, lg, col0, accz, accr, acch);
  #pragma unroll
  for (int nt = 0; nt < 2; ++nt) {
    int col = col0 + nt * 16;
    #pragma unroll
    for (int mt = 0; mt < 4; ++mt)
      #pragma unroll
      for (int j = 0; j < 4; ++j) {
        int row = mt * 16 + lg * 4 + j;
        float rr = fsig(accr[mt][nt][j] + brv[nt]);
        A0[row * 256 + ((((col >> 3) ^ (row & 7)) << 3) | (col & 7))] =
            __float2bfloat16(ph[mt][nt][j] * rr);
      }
  }
  __syncthreads();

  // ---- P6: acch += T @ W_hh (reads A0) ----
  {
    const __hip_bfloat16* WH = wsb + WTHH_OFF;
    const __hip_bfloat16* bh0 = WH + (size_t)col0 * 256 + lg * 8;
    const __hip_bfloat16* bh[2] = { bh0, bh0 + 16 * 256 };
    #pragma unroll
    for (int kb = 0; kb < 8; ++kb) {
      bf16x8 vb[2];
      #pragma unroll
      for (int nt = 0; nt < 2; ++nt) vb[nt] = *(const bf16x8*)(bh[nt] + kb * 32);
      const int gk = kb * 4 + lg;
      bf16x8 a[4];
      #pragma unroll
      for (int mt = 0; mt < 4; ++mt) {
        const int row = mt * 16 + l15;
        a[mt] = *(const bf16x8*)&A0[row * 256 + (gk ^ (row & 7)) * 8];
      }
      #pragma unroll
      for (int nt = 0; nt < 2; ++nt)
        #pragma unroll
        for (int mt = 0; mt < 4; ++mt)
          acch[mt][nt] = __builtin_amdgcn_mfma_f32_16x16x32_bf16(a[mt], vb[nt], acch[mt][nt], 0, 0, 0);
    }
  }

  // ---- epilogue: h = Z*prev_h + (1-Z)*tanh(A_h) ----
  float bzv[2] = { wsf[col0], wsf[col0 + 16] };
  float bhv[2] = { wsf[512 + col0], wsf[512 + col0 + 16] };
  #pragma unroll
  for (int nt = 0; nt < 2; ++nt) {
    int col = col0 + nt * 16;
    #pragma unroll
    for (int mt = 0; mt < 4; ++mt)
      #pragma unroll
      for (int j = 0; j < 4; ++j) {
        int row = mt * 16 + lg * 4 + j;
        float zg = fsig(accz[mt][nt][j] + bzv[nt]);
        float ht = ftanh(acch[mt][nt][j] + bhv[nt]);
        h_out[(size_t)(r0 + row) * DBB + col] = zg * ph[mt][nt][j] + (1.0f - zg) * ht;
      }
  }
}

extern "C" void kernel_launch(void* const* d_in, const int* in_sizes, int n_in,
                              void* d_out, int out_size, void* d_ws, size_t ws_size,
                              hipStream_t stream) {
  const float* z      = (const float*)d_in[0];
  const float* u      = (const float*)d_in[1];
  const float* x      = (const float*)d_in[2];
  const float* prev_h = (const float*)d_in[6];
  const float* w_proj = (const float*)d_in[7];
  const float* b_proj = (const float*)d_in[8];
  const float* w_glob = (const float*)d_in[9];
  const float* b_glob = (const float*)d_in[10];
  const float* W_xz   = (const float*)d_in[11];
  const float* b_xz   = (const float*)d_in[12];
  const float* W_hz   = (const float*)d_in[13];
  const float* b_hz   = (const float*)d_in[14];
  const float* W_xr   = (const float*)d_in[15];
  const float* b_xr   = (const float*)d_in[16];
  const float* W_hr   = (const float*)d_in[17];
  const float* b_hr   = (const float*)d_in[18];
  const float* W_xh   = (const float*)d_in[19];
  const float* b_xh   = (const float*)d_in[20];
  const float* W_hh   = (const float*)d_in[21];
  const float* b_hh   = (const float*)d_in[22];

  __hip_bfloat16* wsb = (__hip_bfloat16*)d_ws;
  float* wsf = (float*)((char*)d_ws + (size_t)WS_BF16_ELEMS * 2);

  float* fused = (float*)d_out;
  float* h_out = fused + (size_t)BGRAPH * 384;

  pack_weights<<<dim3(WS_BF16_ELEMS / 256), dim3(256), 0, stream>>>(
      w_proj, W_xz, W_hz, W_xr, W_hr, W_xh, W_hh,
      b_xz, b_hz, b_xr, b_hr, b_xh, b_hh, wsb, wsf);

  // head first: warms L3 with z before the main pass
  fused_head<<<dim3(BGRAPH), dim3(128), 0, stream>>>(z, u, w_glob, b_glob, fused);

  grnn_main<<<dim3(NNODES / 64), dim3(512), 0, stream>>>(
      z, x, prev_h, b_proj, wsb, wsf, h_out);
}

// Round 3
// 313.406 us; speedup vs baseline: 1.1483x; 1.0234x over previous
//
#include <hip/hip_runtime.h>
#include <hip/hip_bf16.h>

#define NNODES 90112
#define BGRAPH 4096
#define NPG 22
#define DBB 256
#define DNODE 128
#define DPROJ 256
#define DGIN 64
#define DGOUT 128

// ws layout (bf16 elems):
//   [0,        32768)  WTp   [256 cols][128 k]   (w_proj^T)
//   [32768,   622592)  WTg   [768 cols][768 k]   (cols: z|r|h gates; k: z|x_proj|prev_h)
//   [622592,  688128)  WThh  [256 cols][256 k]
// then f32 at byte offset 688128*2: bz[256], br[256], bh[256] (combined biases)
#define WTG_OFF   32768
#define WTHH_OFF  622592
#define WS_BF16_ELEMS 688128

typedef __attribute__((ext_vector_type(8))) short bf16x8;
typedef __attribute__((ext_vector_type(4))) short bf16x4;
typedef __attribute__((ext_vector_type(4))) float f32x4;

__device__ __forceinline__ short f2bf(float f) {
  __hip_bfloat16 h = __float2bfloat16(f);
  return *reinterpret_cast<short*>(&h);
}
__device__ __forceinline__ float bf2f(short s) {
  union { unsigned int u; float f; } c;
  c.u = ((unsigned int)(unsigned short)s) << 16;
  return c.f;
}
__device__ __forceinline__ float fsig(float xv) {
  return __fdividef(1.0f, 1.0f + __expf(-xv));
}
__device__ __forceinline__ float ftanh(float xv) {
  return 1.0f - __fdividef(2.0f, __expf(2.0f * xv) + 1.0f);
}

__global__ void pack_weights(const float* __restrict__ w_proj,
                             const float* __restrict__ W_xz, const float* __restrict__ W_hz,
                             const float* __restrict__ W_xr, const float* __restrict__ W_hr,
                             const float* __restrict__ W_xh, const float* __restrict__ W_hh,
                             const float* __restrict__ b_xz, const float* __restrict__ b_hz,
                             const float* __restrict__ b_xr, const float* __restrict__ b_hr,
                             const float* __restrict__ b_xh, const float* __restrict__ b_hh,
                             __hip_bfloat16* __restrict__ wsb, float* __restrict__ wsf) {
  int i = blockIdx.x * 256 + threadIdx.x;
  if (i < 32768) {
    int c = i >> 7, k = i & 127;                 // WTp[c][k] = w_proj[k][c]
    wsb[i] = __float2bfloat16(w_proj[k * DPROJ + c]);
  } else if (i < WTHH_OFF) {
    int j = i - WTG_OFF;
    int c = j / 768, k = j - c * 768;
    const float* Wx; const float* Wh; int cc;
    if (c < 256)      { Wx = W_xz; Wh = W_hz; cc = c; }
    else if (c < 512) { Wx = W_xr; Wh = W_hr; cc = c - 256; }
    else              { Wx = W_xh; Wh = nullptr; cc = c - 512; }
    float v;
    if (k < 512) v = Wx[k * 256 + cc];
    else         v = Wh ? Wh[(k - 512) * 256 + cc] : 0.0f;
    wsb[i] = __float2bfloat16(v);
  } else if (i < WS_BF16_ELEMS) {
    int j = i - WTHH_OFF;
    int c = j >> 8, k = j & 255;                 // WThh[c][k] = W_hh[k][c]
    wsb[i] = __float2bfloat16(W_hh[k * 256 + c]);
  }
  if (i < 256) {
    wsf[i]       = b_xz[i] + b_hz[i];
    wsf[256 + i] = b_xr[i] + b_hr[i];
    wsf[512 + i] = b_xh[i] + b_hh[i];
  }
}

// fused[b] = [ mean_{22 rows} z , relu(u @ w_glob + b_glob) ]
__global__ void fused_head(const float* __restrict__ z, const float* __restrict__ u,
                           const float* __restrict__ w_glob, const float* __restrict__ b_glob,
                           float* __restrict__ out) {
  int b = blockIdx.x;
  int t = threadIdx.x;  // 128 threads
  __shared__ float us[DGIN];
  if (t < DGIN) us[t] = u[b * DGIN + t];
  __syncthreads();
  const float* zb = z + (size_t)b * NPG * DBB;
  #pragma unroll
  for (int half = 0; half < 2; ++half) {
    int c = t + half * 128;
    float s = 0.f;
    #pragma unroll
    for (int r = 0; r < NPG; ++r) s += zb[r * DBB + c];
    out[(size_t)b * 384 + c] = s * (1.0f / NPG);
  }
  float acc = b_glob[t];
  #pragma unroll
  for (int k = 0; k < DGIN; ++k) acc += us[k] * w_glob[k * DGOUT + t];
  out[(size_t)b * 384 + 256 + t] = fmaxf(acc, 0.f);
}

#define MFMA16(a, b, c) __builtin_amdgcn_mfma_f32_16x16x32_bf16(a, b, c, 0, 0, 0)

// One source-tile sweep (swapped operands: a = weight frags, b = activation frags).
// D layout per lane: act row = (lane&15) within rt-tile, weight cols = lg*4+j within ct-tile.
template<bool DO_H>
__device__ __forceinline__ void gate_pass(
    const __hip_bfloat16* __restrict__ tile,   // [64][256] swizzled activations
    const __hip_bfloat16* __restrict__ WTG, int ksrc,
    int l15, int lg, int c0,
    f32x4 (&accz)[2][4], f32x4 (&accr)[2][4], f32x4 (&acch)[2][4]) {
  const __hip_bfloat16* p0 = WTG + (size_t)(c0 + l15) * 768 + ksrc * 256 + lg * 8;
  #pragma unroll
  for (int kb = 0; kb < 8; ++kb) {
    bf16x8 wz[2], wr[2], wh[2];
    #pragma unroll
    for (int ct = 0; ct < 2; ++ct) {
      const __hip_bfloat16* p = p0 + ct * (16 * 768) + kb * 32;
      wz[ct] = *(const bf16x8*)(p);
      wr[ct] = *(const bf16x8*)(p + (size_t)256 * 768);
      if (DO_H) wh[ct] = *(const bf16x8*)(p + (size_t)512 * 768);
    }
    const int gk = kb * 4 + lg;
    bf16x8 act[4];
    #pragma unroll
    for (int rt = 0; rt < 4; ++rt) {
      const int row = rt * 16 + l15;
      act[rt] = *(const bf16x8*)(tile + row * 256 + ((gk ^ (row & 7)) * 8));
    }
    __builtin_amdgcn_s_setprio(1);
    #pragma unroll
    for (int ct = 0; ct < 2; ++ct)
      #pragma unroll
      for (int rt = 0; rt < 4; ++rt) {
        accz[ct][rt] = MFMA16(wz[ct], act[rt], accz[ct][rt]);
        accr[ct][rt] = MFMA16(wr[ct], act[rt], accr[ct][rt]);
        if (DO_H) acch[ct][rt] = MFMA16(wh[ct], act[rt], acch[ct][rt]);
      }
    __builtin_amdgcn_s_setprio(0);
  }
}

// Fused GRU body: 64 rows/block, 512 threads (8 waves x 32 weight-cols).
__global__ __launch_bounds__(512, 2)
void grnn_main(const float* __restrict__ z, const float* __restrict__ x,
               const float* __restrict__ prev_h, const float* __restrict__ b_proj,
               const __hip_bfloat16* __restrict__ wsb, const float* __restrict__ wsf,
               float* __restrict__ h_out) {
  __shared__ __align__(16) __hip_bfloat16 A0[64 * 256];
  __shared__ __align__(16) __hip_bfloat16 A1[64 * 256];

  const int r0   = blockIdx.x * 64;
  const int tid  = threadIdx.x;
  const int wid  = tid >> 6;
  const int lane = tid & 63;
  const int l15  = lane & 15;
  const int lg   = lane >> 4;
  const int c0   = wid * 32;
  const int lgl  = lg & 1;
  const int cgrpb = (c0 >> 3) + (lg >> 1);   // + ct*2

  // ---- P0: stage x -> A0 (as [64][128]) ----
  #pragma unroll
  for (int i = 0; i < 2; ++i) {
    int g = tid + i * 512;
    int row = g >> 4, c8 = g & 15;
    const float* p = x + (size_t)(r0 + row) * DNODE + c8 * 8;
    float4 f0 = *(const float4*)p;
    float4 f1 = *(const float4*)(p + 4);
    bf16x8 o;
    o[0]=f2bf(f0.x); o[1]=f2bf(f0.y); o[2]=f2bf(f0.z); o[3]=f2bf(f0.w);
    o[4]=f2bf(f1.x); o[5]=f2bf(f1.y); o[6]=f2bf(f1.z); o[7]=f2bf(f1.w);
    *(bf16x8*)&A0[row * 128 + (c8 ^ (row & 7)) * 8] = o;
  }
  __syncthreads();

  // ---- P1: x_proj GEMM (reads A0) overlapped with staging z -> A1 ----
  float4 sl[8];
  #pragma unroll
  for (int i = 0; i < 4; ++i) {
    int g = tid + i * 512;
    int row = g >> 5, c8 = g & 31;
    const float* p = z + (size_t)(r0 + row) * DBB + c8 * 8;
    sl[2 * i]     = *(const float4*)p;
    sl[2 * i + 1] = *(const float4*)(p + 4);
  }
  f32x4 accp[2][4] = {};
  {
    const __hip_bfloat16* bp0 = wsb + (size_t)(c0 + l15) * DNODE + lg * 8;
    #pragma unroll
    for (int kb = 0; kb < 4; ++kb) {
      bf16x8 wp[2];
      #pragma unroll
      for (int ct = 0; ct < 2; ++ct) wp[ct] = *(const bf16x8*)(bp0 + ct * (16 * DNODE) + kb * 32);
      const int gk = kb * 4 + lg;
      bf16x8 act[4];
      #pragma unroll
      for (int rt = 0; rt < 4; ++rt) {
        const int row = rt * 16 + l15;
        act[rt] = *(const bf16x8*)&A0[row * 128 + (gk ^ (row & 7)) * 8];
      }
      __builtin_amdgcn_s_setprio(1);
      #pragma unroll
      for (int ct = 0; ct < 2; ++ct)
        #pragma unroll
        for (int rt = 0; rt < 4; ++rt)
          accp[ct][rt] = MFMA16(wp[ct], act[rt], accp[ct][rt]);
      __builtin_amdgcn_s_setprio(0);
    }
  }
  #pragma unroll
  for (int i = 0; i < 4; ++i) {
    int g = tid + i * 512;
    int row = g >> 5, c8 = g & 31;
    float4 f0 = sl[2 * i], f1 = sl[2 * i + 1];
    bf16x8 o;
    o[0]=f2bf(f0.x); o[1]=f2bf(f0.y); o[2]=f2bf(f0.z); o[3]=f2bf(f0.w);
    o[4]=f2bf(f1.x); o[5]=f2bf(f1.y); o[6]=f2bf(f1.z); o[7]=f2bf(f1.w);
    *(bf16x8*)&A1[row * 256 + (c8 ^ (row & 7)) * 8] = o;
  }
  __syncthreads();

  // ---- P2: write xp -> A0 (x fully consumed). Lane owns 4 consecutive cols. ----
  {
    #pragma unroll
    for (int ct = 0; ct < 2; ++ct) {
      float4 bp4 = *(const float4*)&b_proj[c0 + ct * 16 + lg * 4];
      int cgrp = cgrpb + ct * 2;
      #pragma unroll
      for (int rt = 0; rt < 4; ++rt) {
        int r = rt * 16 + l15;
        bf16x4 o;
        o[0] = f2bf(fmaxf(accp[ct][rt][0] + bp4.x, 0.f));
        o[1] = f2bf(fmaxf(accp[ct][rt][1] + bp4.y, 0.f));
        o[2] = f2bf(fmaxf(accp[ct][rt][2] + bp4.z, 0.f));
        o[3] = f2bf(fmaxf(accp[ct][rt][3] + bp4.w, 0.f));
        *(bf16x4*)&A0[r * 256 + ((cgrp ^ (r & 7)) * 8) + lgl * 4] = o;
      }
    }
  }
  __syncthreads();

  const __hip_bfloat16* WTG = wsb + WTG_OFF;
  f32x4 accz[2][4] = {}, accr[2][4] = {}, acch[2][4] = {};

  // ---- P3: z-tile sweep (reads A1) ----
  gate_pass<true>(A1, WTG, 0, l15, lg, c0, accz, accr, acch);
  __syncthreads();

  // ---- P4: xp sweep (reads A0) overlapped with staging prev_h -> A1 ----
  #pragma unroll
  for (int i = 0; i < 4; ++i) {
    int g = tid + i * 512;
    int row = g >> 5, c8 = g & 31;
    const float* p = prev_h + (size_t)(r0 + row) * DBB + c8 * 8;
    sl[2 * i]     = *(const float4*)p;
    sl[2 * i + 1] = *(const float4*)(p + 4);
  }
  gate_pass<true>(A0, WTG, 1, l15, lg, c0, accz, accr, acch);
  #pragma unroll
  for (int i = 0; i < 4; ++i) {
    int g = tid + i * 512;
    int row = g >> 5, c8 = g & 31;
    float4 f0 = sl[2 * i], f1 = sl[2 * i + 1];
    bf16x8 o;
    o[0]=f2bf(f0.x); o[1]=f2bf(f0.y); o[2]=f2bf(f0.z); o[3]=f2bf(f0.w);
    o[4]=f2bf(f1.x); o[5]=f2bf(f1.y); o[6]=f2bf(f1.z); o[7]=f2bf(f1.w);
    *(bf16x8*)&A1[row * 256 + (c8 ^ (row & 7)) * 8] = o;
  }
  __syncthreads();

  // ---- P5: prev_h sweep (reads A1, z/r only); T = ph*sigmoid(Ar) -> A0 ----
  gate_pass<false>(A1, WTG, 2, l15, lg, c0, accz, accr, acch);
  #pragma unroll
  for (int ct = 0; ct < 2; ++ct) {
    float4 br4 = *(const float4*)&wsf[256 + c0 + ct * 16 + lg * 4];
    int cgrp = cgrpb + ct * 2;
    #pragma unroll
    for (int rt = 0; rt < 4; ++rt) {
      int r = rt * 16 + l15;
      int off = r * 256 + ((cgrp ^ (r & 7)) * 8) + lgl * 4;
      bf16x4 p4 = *(const bf16x4*)&A1[off];
      bf16x4 o;
      o[0] = f2bf(bf2f(p4[0]) * fsig(accr[ct][rt][0] + br4.x));
      o[1] = f2bf(bf2f(p4[1]) * fsig(accr[ct][rt][1] + br4.y));
      o[2] = f2bf(bf2f(p4[2]) * fsig(accr[ct][rt][2] + br4.z));
      o[3] = f2bf(bf2f(p4[3]) * fsig(accr[ct][rt][3] + br4.w));
      *(bf16x4*)&A0[off] = o;
    }
  }
  __syncthreads();

  // ---- P6: acch += T @ W_hh (reads A0) ----
  {
    const __hip_bfloat16* WH = wsb + WTHH_OFF;
    const __hip_bfloat16* wh0 = WH + (size_t)(c0 + l15) * 256 + lg * 8;
    #pragma unroll
    for (int kb = 0; kb < 8; ++kb) {
      bf16x8 wv[2];
      #pragma unroll
      for (int ct = 0; ct < 2; ++ct) wv[ct] = *(const bf16x8*)(wh0 + ct * (16 * 256) + kb * 32);
      const int gk = kb * 4 + lg;
      bf16x8 act[4];
      #pragma unroll
      for (int rt = 0; rt < 4; ++rt) {
        const int row = rt * 16 + l15;
        act[rt] = *(const bf16x8*)&A0[row * 256 + (gk ^ (row & 7)) * 8];
      }
      __builtin_amdgcn_s_setprio(1);
      #pragma unroll
      for (int ct = 0; ct < 2; ++ct)
        #pragma unroll
        for (int rt = 0; rt < 4; ++rt)
          acch[ct][rt] = MFMA16(wv[ct], act[rt], acch[ct][rt]);
      __builtin_amdgcn_s_setprio(0);
    }
  }

  // ---- epilogue: h = Z*ph + (1-Z)*tanh(A_h); ph from LDS; coalesced f32x4 stores ----
  #pragma unroll
  for (int ct = 0; ct < 2; ++ct) {
    float4 bz4 = *(const float4*)&wsf[c0 + ct * 16 + lg * 4];
    float4 bh4 = *(const float4*)&wsf[512 + c0 + ct * 16 + lg * 4];
    int cgrp = cgrpb + ct * 2;
    #pragma unroll
    for (int rt = 0; rt < 4; ++rt) {
      int r = rt * 16 + l15;
      bf16x4 p4 = *(const bf16x4*)&A1[r * 256 + ((cgrp ^ (r & 7)) * 8) + lgl * 4];
      float4 hv;
      {
        float zg = fsig(accz[ct][rt][0] + bz4.x);
        hv.x = zg * bf2f(p4[0]) + (1.f - zg) * ftanh(acch[ct][rt][0] + bh4.x);
        zg = fsig(accz[ct][rt][1] + bz4.y);
        hv.y = zg * bf2f(p4[1]) + (1.f - zg) * ftanh(acch[ct][rt][1] + bh4.y);
        zg = fsig(accz[ct][rt][2] + bz4.z);
        hv.z = zg * bf2f(p4[2]) + (1.f - zg) * ftanh(acch[ct][rt][2] + bh4.z);
        zg = fsig(accz[ct][rt][3] + bz4.w);
        hv.w = zg * bf2f(p4[3]) + (1.f - zg) * ftanh(acch[ct][rt][3] + bh4.w);
      }
      *(float4*)&h_out[(size_t)(r0 + r) * DBB + c0 + ct * 16 + lg * 4] = hv;
    }
  }
}

extern "C" void kernel_launch(void* const* d_in, const int* in_sizes, int n_in,
                              void* d_out, int out_size, void* d_ws, size_t ws_size,
                              hipStream_t stream) {
  const float* z      = (const float*)d_in[0];
  const float* u      = (const float*)d_in[1];
  const float* x      = (const float*)d_in[2];
  const float* prev_h = (const float*)d_in[6];
  const float* w_proj = (const float*)d_in[7];
  const float* b_proj = (const float*)d_in[8];
  const float* w_glob = (const float*)d_in[9];
  const float* b_glob = (const float*)d_in[10];
  const float* W_xz   = (const float*)d_in[11];
  const float* b_xz   = (const float*)d_in[12];
  const float* W_hz   = (const float*)d_in[13];
  const float* b_hz   = (const float*)d_in[14];
  const float* W_xr   = (const float*)d_in[15];
  const float* b_xr   = (const float*)d_in[16];
  const float* W_hr   = (const float*)d_in[17];
  const float* b_hr   = (const float*)d_in[18];
  const float* W_xh   = (const float*)d_in[19];
  const float* b_xh   = (const float*)d_in[20];
  const float* W_hh   = (const float*)d_in[21];
  const float* b_hh   = (const float*)d_in[22];

  __hip_bfloat16* wsb = (__hip_bfloat16*)d_ws;
  float* wsf = (float*)((char*)d_ws + (size_t)WS_BF16_ELEMS * 2);

  float* fused = (float*)d_out;
  float* h_out = fused + (size_t)BGRAPH * 384;

  pack_weights<<<dim3(WS_BF16_ELEMS / 256), dim3(256), 0, stream>>>(
      w_proj, W_xz, W_hz, W_xr, W_hr, W_xh, W_hh,
      b_xz, b_hz, b_xr, b_hr, b_xh, b_hh, wsb, wsf);

  // head first: warms L3 with z before the main pass
  fused_head<<<dim3(BGRAPH), dim3(128), 0, stream>>>(z, u, w_glob, b_glob, fused);

  grnn_main<<<dim3(NNODES / 64), dim3(512), 0, stream>>>(
      z, x, prev_h, b_proj, wsb, wsf, h_out);
}

// Round 4
// 305.595 us; speedup vs baseline: 1.1776x; 1.0256x over previous
//
#include <hip/hip_runtime.h>
#include <hip/hip_bf16.h>

#define NNODES 90112
#define BGRAPH 4096
#define NPG 22
#define DBB 256
#define DNODE 128
#define DPROJ 256
#define DGIN 64
#define DGOUT 128

// ws layout (bf16 elems):
//   [0,        32768)  WTp   [256 cols][128 k]   (w_proj^T)
//   [32768,   622592)  WTg   [768 cols][768 k]   (cols: z|r|h gates; k: z|x_proj|prev_h)
//   [622592,  688128)  WThh  [256 cols][256 k]
// then f32 at byte offset 688128*2: bz[256], br[256], bh[256] (combined biases)
#define WTG_OFF   32768
#define WTHH_OFF  622592
#define WS_BF16_ELEMS 688128

typedef __attribute__((ext_vector_type(8))) short bf16x8;
typedef __attribute__((ext_vector_type(4))) short bf16x4;
typedef __attribute__((ext_vector_type(4))) float f32x4;

__device__ __forceinline__ short f2bf(float f) {
  __hip_bfloat16 h = __float2bfloat16(f);
  return *reinterpret_cast<short*>(&h);
}
__device__ __forceinline__ float bf2f(short s) {
  union { unsigned int u; float f; } c;
  c.u = ((unsigned int)(unsigned short)s) << 16;
  return c.f;
}
__device__ __forceinline__ float fsig(float xv) {
  return __fdividef(1.0f, 1.0f + __expf(-xv));
}
__device__ __forceinline__ float ftanh(float xv) {
  return 1.0f - __fdividef(2.0f, __expf(2.0f * xv) + 1.0f);
}

__global__ void pack_weights(const float* __restrict__ w_proj,
                             const float* __restrict__ W_xz, const float* __restrict__ W_hz,
                             const float* __restrict__ W_xr, const float* __restrict__ W_hr,
                             const float* __restrict__ W_xh, const float* __restrict__ W_hh,
                             const float* __restrict__ b_xz, const float* __restrict__ b_hz,
                             const float* __restrict__ b_xr, const float* __restrict__ b_hr,
                             const float* __restrict__ b_xh, const float* __restrict__ b_hh,
                             __hip_bfloat16* __restrict__ wsb, float* __restrict__ wsf) {
  int i = blockIdx.x * 256 + threadIdx.x;
  if (i < 32768) {
    int c = i >> 7, k = i & 127;                 // WTp[c][k] = w_proj[k][c]
    wsb[i] = __float2bfloat16(w_proj[k * DPROJ + c]);
  } else if (i < WTHH_OFF) {
    int j = i - WTG_OFF;
    int c = j / 768, k = j - c * 768;
    const float* Wx; const float* Wh; int cc;
    if (c < 256)      { Wx = W_xz; Wh = W_hz; cc = c; }
    else if (c < 512) { Wx = W_xr; Wh = W_hr; cc = c - 256; }
    else              { Wx = W_xh; Wh = nullptr; cc = c - 512; }
    float v;
    if (k < 512) v = Wx[k * 256 + cc];
    else         v = Wh ? Wh[(k - 512) * 256 + cc] : 0.0f;
    wsb[i] = __float2bfloat16(v);
  } else if (i < WS_BF16_ELEMS) {
    int j = i - WTHH_OFF;
    int c = j >> 8, k = j & 255;                 // WThh[c][k] = W_hh[k][c]
    wsb[i] = __float2bfloat16(W_hh[k * 256 + c]);
  }
  if (i < 256) {
    wsf[i]       = b_xz[i] + b_hz[i];
    wsf[256 + i] = b_xr[i] + b_hr[i];
    wsf[512 + i] = b_xh[i] + b_hh[i];
  }
}

// fused[b] = [ mean_{22 rows} z , relu(u @ w_glob + b_glob) ]
__global__ void fused_head(const float* __restrict__ z, const float* __restrict__ u,
                           const float* __restrict__ w_glob, const float* __restrict__ b_glob,
                           float* __restrict__ out) {
  int b = blockIdx.x;
  int t = threadIdx.x;  // 128 threads
  __shared__ float us[DGIN];
  if (t < DGIN) us[t] = u[b * DGIN + t];
  __syncthreads();
  const float* zb = z + (size_t)b * NPG * DBB;
  #pragma unroll
  for (int half = 0; half < 2; ++half) {
    int c = t + half * 128;
    float s = 0.f;
    #pragma unroll
    for (int r = 0; r < NPG; ++r) s += zb[r * DBB + c];
    out[(size_t)b * 384 + c] = s * (1.0f / NPG);
  }
  float acc = b_glob[t];
  #pragma unroll
  for (int k = 0; k < DGIN; ++k) acc += us[k] * w_glob[k * DGOUT + t];
  out[(size_t)b * 384 + 256 + t] = fmaxf(acc, 0.f);
}

#define MFMA16(a, b, c) __builtin_amdgcn_mfma_f32_16x16x32_bf16(a, b, c, 0, 0, 0)

// One source-tile K=256 sweep. a-operand = weights (wave's 16 cols), b = act rows.
// D per lane: act row = rt*16 + (lane&15); weight col = c0 + (lane>>4)*4 + j.
template<bool DO_H>
__device__ __forceinline__ void gate_pass(
    const __hip_bfloat16* __restrict__ tile,   // [64][256] swizzled activations
    const __hip_bfloat16* __restrict__ WTG, int ksrc,
    int l15, int lg, int c0,
    f32x4 (&accz)[4], f32x4 (&accr)[4], f32x4 (&acch)[4]) {
  const __hip_bfloat16* p0 = WTG + (size_t)(c0 + l15) * 768 + ksrc * 256 + lg * 8;
  #pragma unroll
  for (int kb = 0; kb < 8; ++kb) {
    bf16x8 wz = *(const bf16x8*)(p0 + kb * 32);
    bf16x8 wr = *(const bf16x8*)(p0 + (size_t)256 * 768 + kb * 32);
    bf16x8 wh;
    if (DO_H) wh = *(const bf16x8*)(p0 + (size_t)512 * 768 + kb * 32);
    const int gk = kb * 4 + lg;
    bf16x8 act[4];
    #pragma unroll
    for (int rt = 0; rt < 4; ++rt) {
      const int row = rt * 16 + l15;
      act[rt] = *(const bf16x8*)(tile + row * 256 + ((gk ^ (row & 7)) * 8));
    }
    __builtin_amdgcn_s_setprio(1);
    #pragma unroll
    for (int rt = 0; rt < 4; ++rt) {
      accz[rt] = MFMA16(wz, act[rt], accz[rt]);
      accr[rt] = MFMA16(wr, act[rt], accr[rt]);
      if (DO_H) acch[rt] = MFMA16(wh, act[rt], acch[rt]);
    }
    __builtin_amdgcn_s_setprio(0);
  }
}

// Fused GRU body: 64 rows/block, 1024 threads = 16 waves, each wave owns 16
// weight-cols x 64 rows (48 f32 acc/lane -> <=128 regs -> 4 waves/SIMD).
// All four source tiles live in LDS simultaneously (112 KB) so the three
// gate sweeps run back-to-back with no barriers between them.
__global__ __launch_bounds__(1024)
void grnn_main(const float* __restrict__ z, const float* __restrict__ x,
               const float* __restrict__ prev_h, const float* __restrict__ b_proj,
               const __hip_bfloat16* __restrict__ wsb, const float* __restrict__ wsf,
               float* __restrict__ h_out) {
  __shared__ __align__(16) __hip_bfloat16 Xs[64 * 128];
  __shared__ __align__(16) __hip_bfloat16 Zs[64 * 256];   // reused as T after z-sweep
  __shared__ __align__(16) __hip_bfloat16 XPs[64 * 256];
  __shared__ __align__(16) __hip_bfloat16 PHs[64 * 256];

  const int r0   = blockIdx.x * 64;
  const int tid  = threadIdx.x;
  const int wid  = tid >> 6;          // 0..15
  const int lane = tid & 63;
  const int l15  = lane & 15;
  const int lg   = lane >> 4;         // 0..3
  const int c0   = wid * 16;          // wave's 16-col slice
  const int cgrp = (c0 >> 3) + (lg >> 1);   // granule of lane's 4-col quad
  const int lgl  = (lg & 1) * 4;            // elem offset within granule

  // ---- P0: stage x -> Xs ([64][128], 16B-granule XOR swizzle) ----
  {
    int row = tid >> 4, c8 = tid & 15;
    const float* p = x + (size_t)(r0 + row) * DNODE + c8 * 8;
    float4 f0 = *(const float4*)p;
    float4 f1 = *(const float4*)(p + 4);
    bf16x8 o;
    o[0]=f2bf(f0.x); o[1]=f2bf(f0.y); o[2]=f2bf(f0.z); o[3]=f2bf(f0.w);
    o[4]=f2bf(f1.x); o[5]=f2bf(f1.y); o[6]=f2bf(f1.z); o[7]=f2bf(f1.w);
    *(bf16x8*)&Xs[row * 128 + (c8 ^ (row & 7)) * 8] = o;
  }
  __syncthreads();

  // ---- P1: issue z+ph loads, x_proj GEMM under them, then LDS writes ----
  float4 slz[4], slp[4];
  #pragma unroll
  for (int i = 0; i < 2; ++i) {
    int g = tid + i * 1024;
    int row = g >> 5, c8 = g & 31;
    const float* pz = z + (size_t)(r0 + row) * DBB + c8 * 8;
    const float* pp = prev_h + (size_t)(r0 + row) * DBB + c8 * 8;
    slz[2 * i]     = *(const float4*)pz;
    slz[2 * i + 1] = *(const float4*)(pz + 4);
    slp[2 * i]     = *(const float4*)pp;
    slp[2 * i + 1] = *(const float4*)(pp + 4);
  }
  f32x4 accp[4] = {};
  {
    const __hip_bfloat16* wp0 = wsb + (size_t)(c0 + l15) * DNODE + lg * 8;
    #pragma unroll
    for (int kb = 0; kb < 4; ++kb) {
      bf16x8 wp = *(const bf16x8*)(wp0 + kb * 32);
      const int gk = kb * 4 + lg;
      bf16x8 act[4];
      #pragma unroll
      for (int rt = 0; rt < 4; ++rt) {
        const int row = rt * 16 + l15;
        act[rt] = *(const bf16x8*)&Xs[row * 128 + (gk ^ (row & 7)) * 8];
      }
      __builtin_amdgcn_s_setprio(1);
      #pragma unroll
      for (int rt = 0; rt < 4; ++rt)
        accp[rt] = MFMA16(wp, act[rt], accp[rt]);
      __builtin_amdgcn_s_setprio(0);
    }
  }
  #pragma unroll
  for (int i = 0; i < 2; ++i) {
    int g = tid + i * 1024;
    int row = g >> 5, c8 = g & 31;
    int off = row * 256 + (c8 ^ (row & 7)) * 8;
    float4 f0 = slz[2 * i], f1 = slz[2 * i + 1];
    bf16x8 o;
    o[0]=f2bf(f0.x); o[1]=f2bf(f0.y); o[2]=f2bf(f0.z); o[3]=f2bf(f0.w);
    o[4]=f2bf(f1.x); o[5]=f2bf(f1.y); o[6]=f2bf(f1.z); o[7]=f2bf(f1.w);
    *(bf16x8*)&Zs[off] = o;
    f0 = slp[2 * i]; f1 = slp[2 * i + 1];
    o[0]=f2bf(f0.x); o[1]=f2bf(f0.y); o[2]=f2bf(f0.z); o[3]=f2bf(f0.w);
    o[4]=f2bf(f1.x); o[5]=f2bf(f1.y); o[6]=f2bf(f1.z); o[7]=f2bf(f1.w);
    *(bf16x8*)&PHs[off] = o;
  }
  {
    float4 bp4 = *(const float4*)&b_proj[c0 + lg * 4];
    #pragma unroll
    for (int rt = 0; rt < 4; ++rt) {
      int r = rt * 16 + l15;
      bf16x4 o;
      o[0] = f2bf(fmaxf(accp[rt][0] + bp4.x, 0.f));
      o[1] = f2bf(fmaxf(accp[rt][1] + bp4.y, 0.f));
      o[2] = f2bf(fmaxf(accp[rt][2] + bp4.z, 0.f));
      o[3] = f2bf(fmaxf(accp[rt][3] + bp4.w, 0.f));
      *(bf16x4*)&XPs[r * 256 + ((cgrp ^ (r & 7)) * 8) + lgl] = o;
    }
  }
  __syncthreads();

  // ---- P2: fused gate sweeps (no barriers between sources) ----
  const __hip_bfloat16* WTG = wsb + WTG_OFF;
  f32x4 accz[4] = {}, accr[4] = {}, acch[4] = {};
  gate_pass<true >(Zs,  WTG, 0, l15, lg, c0, accz, accr, acch);
  gate_pass<true >(XPs, WTG, 1, l15, lg, c0, accz, accr, acch);
  gate_pass<false>(PHs, WTG, 2, l15, lg, c0, accz, accr, acch);

  // T = ph * sigmoid(A_r + br) -> Zs (z tile fully consumed)
  {
    float4 br4 = *(const float4*)&wsf[256 + c0 + lg * 4];
    #pragma unroll
    for (int rt = 0; rt < 4; ++rt) {
      int r = rt * 16 + l15;
      int off = r * 256 + ((cgrp ^ (r & 7)) * 8) + lgl;
      bf16x4 p4 = *(const bf16x4*)&PHs[off];
      bf16x4 o;
      o[0] = f2bf(bf2f(p4[0]) * fsig(accr[rt][0] + br4.x));
      o[1] = f2bf(bf2f(p4[1]) * fsig(accr[rt][1] + br4.y));
      o[2] = f2bf(bf2f(p4[2]) * fsig(accr[rt][2] + br4.z));
      o[3] = f2bf(bf2f(p4[3]) * fsig(accr[rt][3] + br4.w));
      *(bf16x4*)&Zs[off] = o;
    }
  }
  __syncthreads();

  // ---- P3: acch += T @ W_hh (T in Zs) ----
  {
    const __hip_bfloat16* wh0 = wsb + WTHH_OFF + (size_t)(c0 + l15) * 256 + lg * 8;
    #pragma unroll
    for (int kb = 0; kb < 8; ++kb) {
      bf16x8 wv = *(const bf16x8*)(wh0 + kb * 32);
      const int gk = kb * 4 + lg;
      bf16x8 act[4];
      #pragma unroll
      for (int rt = 0; rt < 4; ++rt) {
        const int row = rt * 16 + l15;
        act[rt] = *(const bf16x8*)&Zs[row * 256 + (gk ^ (row & 7)) * 8];
      }
      __builtin_amdgcn_s_setprio(1);
      #pragma unroll
      for (int rt = 0; rt < 4; ++rt)
        acch[rt] = MFMA16(wv, act[rt], acch[rt]);
      __builtin_amdgcn_s_setprio(0);
    }
  }

  // ---- epilogue: h = Z*ph + (1-Z)*tanh(A_h); coalesced float4 stores ----
  {
    float4 bz4 = *(const float4*)&wsf[c0 + lg * 4];
    float4 bh4 = *(const float4*)&wsf[512 + c0 + lg * 4];
    #pragma unroll
    for (int rt = 0; rt < 4; ++rt) {
      int r = rt * 16 + l15;
      bf16x4 p4 = *(const bf16x4*)&PHs[r * 256 + ((cgrp ^ (r & 7)) * 8) + lgl];
      float4 hv;
      float zg = fsig(accz[rt][0] + bz4.x);
      hv.x = zg * bf2f(p4[0]) + (1.f - zg) * ftanh(acch[rt][0] + bh4.x);
      zg = fsig(accz[rt][1] + bz4.y);
      hv.y = zg * bf2f(p4[1]) + (1.f - zg) * ftanh(acch[rt][1] + bh4.y);
      zg = fsig(accz[rt][2] + bz4.z);
      hv.z = zg * bf2f(p4[2]) + (1.f - zg) * ftanh(acch[rt][2] + bh4.z);
      zg = fsig(accz[rt][3] + bz4.w);
      hv.w = zg * bf2f(p4[3]) + (1.f - zg) * ftanh(acch[rt][3] + bh4.w);
      *(float4*)&h_out[(size_t)(r0 + r) * DBB + c0 + lg * 4] = hv;
    }
  }
}

extern "C" void kernel_launch(void* const* d_in, const int* in_sizes, int n_in,
                              void* d_out, int out_size, void* d_ws, size_t ws_size,
                              hipStream_t stream) {
  const float* z      = (const float*)d_in[0];
  const float* u      = (const float*)d_in[1];
  const float* x      = (const float*)d_in[2];
  const float* prev_h = (const float*)d_in[6];
  const float* w_proj = (const float*)d_in[7];
  const float* b_proj = (const float*)d_in[8];
  const float* w_glob = (const float*)d_in[9];
  const float* b_glob = (const float*)d_in[10];
  const float* W_xz   = (const float*)d_in[11];
  const float* b_xz   = (const float*)d_in[12];
  const float* W_hz   = (const float*)d_in[13];
  const float* b_hz   = (const float*)d_in[14];
  const float* W_xr   = (const float*)d_in[15];
  const float* b_xr   = (const float*)d_in[16];
  const float* W_hr   = (const float*)d_in[17];
  const float* b_hr   = (const float*)d_in[18];
  const float* W_xh   = (const float*)d_in[19];
  const float* b_xh   = (const float*)d_in[20];
  const float* W_hh   = (const float*)d_in[21];
  const float* b_hh   = (const float*)d_in[22];

  __hip_bfloat16* wsb = (__hip_bfloat16*)d_ws;
  float* wsf = (float*)((char*)d_ws + (size_t)WS_BF16_ELEMS * 2);

  float* fused = (float*)d_out;
  float* h_out = fused + (size_t)BGRAPH * 384;

  pack_weights<<<dim3(WS_BF16_ELEMS / 256), dim3(256), 0, stream>>>(
      w_proj, W_xz, W_hz, W_xr, W_hr, W_xh, W_hh,
      b_xz, b_hz, b_xr, b_hr, b_xh, b_hh, wsb, wsf);

  // head first: warms L3 with z before the main pass
  fused_head<<<dim3(BGRAPH), dim3(128), 0, stream>>>(z, u, w_glob, b_glob, fused);

  grnn_main<<<dim3(NNODES / 64), dim3(1024), 0, stream>>>(
      z, x, prev_h, b_proj, wsb, wsf, h_out);
}